// Round 21
// baseline (504.843 us; speedup 1.0000x reference)
//
#include <hip/hip_runtime.h>

// Problem constants
#define HDIM 1024
#define IDIM 2816
#define NEXP 8
#define NTOK 4096      // B*S
#define NROWS 8192     // NTOK * K(=2)
#define RPAD 8320      // Xg/hbuf pad rows
#define MAXT 71        // max total 128-row tiles
#define GU_NYT 44      // 2*IDIM/128
#define GU_TG 8        // gateup supertile: t-group size
#define GU_NTG 9       // ceil(MAXT/GU_TG)
#define GU_NWG (GU_NTG * GU_NYT * GU_TG)   // 3168 = 8*396
#define DN_NWG 576                         // 8 XCD * 9 tg * 8 ny
#define TLDP 66        // transpose LDS pad (shorts), 128x64 tile -> 16.9KB
#define N_TGU 5632     // 2 kinds * 8 experts * 352 tiles (128x64)
#define N_GATE 1024    // NTOK/4  (gating blocks FIRST in the prep grid)
#define N_TD 2816      // Wd transpose tiles (352 * 8 experts)
#define N_MERGED 5632  // interleaved region: 2816 gateup + 2816 t_d in 8-groups

typedef short bf16x8 __attribute__((ext_vector_type(8)));
typedef float f32x4 __attribute__((ext_vector_type(4)));
typedef unsigned short u16x8 __attribute__((ext_vector_type(8)));

static __device__ __forceinline__ float bf2f(unsigned int u) {
    union { unsigned int i; float f; } v; v.i = u << 16; return v.f;
}
static __device__ __forceinline__ unsigned short f2bf(float f) {
    union { float f; unsigned int i; } v; v.f = f;
    return (unsigned short)((v.i + 0x7fffu + ((v.i >> 16) & 1u)) >> 16);  // RNE
}

// async global->LDS, 16B/lane; LDS dest = wave-uniform base + lane*16
static __device__ __forceinline__ void gload16(const void* g, void* l) {
    __builtin_amdgcn_global_load_lds(
        (const __attribute__((address_space(1))) unsigned int*)g,
        (__attribute__((address_space(3))) unsigned int*)l, 16, 0, 0);
}

// ---------------------------------------------------------------------------
// transpose phase-1: coalesced 128x64 fp32 tile read (8192 floats;
// 256 thr x 8 q x 4 floats). Per wave instr: 1 KB over 4 rows (256B/row).
// ---------------------------------------------------------------------------
static __device__ __forceinline__ void tp_read_tile64(
    const float* __restrict__ sp, int C, int tid, unsigned short* lds)
{
#pragma unroll
    for (int q = 0; q < 8; ++q) {
        int idx = q * 1024 + tid * 4;
        int r = idx >> 6, cc = idx & 63;
        float4 v = *reinterpret_cast<const float4*>(sp + (size_t)r * C + cc);
        unsigned w0 = (unsigned)f2bf(v.x) | ((unsigned)f2bf(v.y) << 16);
        unsigned w1 = (unsigned)f2bf(v.z) | ((unsigned)f2bf(v.w) << 16);
        unsigned* lp = reinterpret_cast<unsigned*>(&lds[r * TLDP + cc]);
        lp[0] = w0; lp[1] = w1;
    }
}

// ---------------------------------------------------------------------------
// 1) Prep: gating (blocks [0,N_GATE) FIRST) + Wg/Wu transpose.
//    128x64 tiles (16.9KB LDS -> 8 blocks/CU).  (r20-proven, 153 us)
// ---------------------------------------------------------------------------
__global__ __launch_bounds__(256) void prep_kernel(
    const float* __restrict__ Wg, const float* __restrict__ Wu,
    unsigned short* __restrict__ W2,
    const float* __restrict__ x, const float* __restrict__ Wgate,
    const float* __restrict__ bgate, float* __restrict__ logits_out,
    int* __restrict__ counts, int* __restrict__ topi, float* __restrict__ topv)
{
    __shared__ unsigned short lds[128 * TLDP];
    const int b = blockIdx.x;
    const int tid = threadIdx.x;

    if (b >= N_GATE) {
        const int tno = b - N_GATE;
        const int kind = tno / (NEXP * 352);
        const int rem = tno % (NEXP * 352);
        const int e = rem / 352;
        const int tt = rem % 352;
        const int tr = tt / 44, tc = tt % 44;   // tr over H(8), tc over I(44)

        const float* s0 = (kind ? Wu : Wg) + (size_t)e * HDIM * IDIM;
        tp_read_tile64(s0 + (size_t)(tr * 128) * IDIM + tc * 64, IDIM, tid, lds);
        __syncthreads();
        const int g = tid & 15;
        unsigned short* d0 = W2 + (size_t)e * 2 * IDIM * HDIM + tr * 128 + g * 8;
#pragma unroll
        for (int cb = 0; cb < 4; ++cb) {
            int c = cb * 16 + (tid >> 4);       // i within tile, 0..63
            u16x8 o;
#pragma unroll
            for (int jj = 0; jj < 8; ++jj) o[jj] = lds[(g * 8 + jj) * TLDP + c];
            int i = tc * 64 + c;
            int r2 = ((i >> 4) << 5) + (kind << 4) + (i & 15);
            *reinterpret_cast<u16x8*>(d0 + (size_t)r2 * HDIM) = o;
        }
        return;
    }

    // ---- gating: 4 tokens per block, fp64 accumulate for stable top-2
    int wave = (b << 2) + (tid >> 6);
    int lane = tid & 63;
    if (wave >= NTOK) return;
    const float* xr = x + (size_t)wave * HDIM;

    double acc[NEXP];
#pragma unroll
    for (int e = 0; e < NEXP; ++e) acc[e] = 0.0;
    for (int it = 0; it < HDIM / 64; ++it) {
        int h = lane + (it << 6);
        float xv = xr[h];
        const float* wr = Wgate + (size_t)h * NEXP;
#pragma unroll
        for (int e = 0; e < NEXP; ++e) acc[e] += (double)xv * (double)wr[e];
    }
#pragma unroll
    for (int e = 0; e < NEXP; ++e) {
        double v = acc[e];
        for (int off = 32; off; off >>= 1) v += __shfl_xor(v, off, 64);
        acc[e] = v + (double)bgate[e];
    }
    float lf[NEXP];
#pragma unroll
    for (int e = 0; e < NEXP; ++e) lf[e] = (float)acc[e];

    if (lane < NEXP) logits_out[(size_t)wave * NEXP + lane] = lf[lane];

    if (lane == 0) {
        int i1 = 0; float v1 = lf[0];
#pragma unroll
        for (int e = 1; e < NEXP; ++e) if (lf[e] > v1) { v1 = lf[e]; i1 = e; }
        int i2 = -1; float v2 = -3.0e38f;
#pragma unroll
        for (int e = 0; e < NEXP; ++e) {
            if (e == i1) continue;
            if (lf[e] > v2) { v2 = lf[e]; i2 = e; }
        }
        topi[wave * 2 + 0] = i1; topv[wave * 2 + 0] = v1;
        topi[wave * 2 + 1] = i2; topv[wave * 2 + 1] = v2;
        atomicAdd(&counts[i1], 1);
        atomicAdd(&counts[i2], 1);
    }
}

// ---------------------------------------------------------------------------
// 2) Offsets + device-built tile table (e, m0) per 128-row tile
// ---------------------------------------------------------------------------
__global__ void offsets_kernel(const int* __restrict__ counts,
                               int* __restrict__ offs, int* __restrict__ cursor,
                               int* __restrict__ ntile, int* __restrict__ te,
                               int* __restrict__ tm0)
{
    if (threadIdx.x == 0 && blockIdx.x == 0) {
        int s = 0;
        for (int e = 0; e < NEXP; ++e) { offs[e] = s; cursor[e] = s; s += counts[e]; }
        offs[NEXP] = s;
        int nt = 0;
        for (int e = 0; e < NEXP; ++e) {
            int c = counts[e], base = offs[e];
            for (int mt = 0; mt * 128 < c; ++mt) { te[nt] = e; tm0[nt] = base + mt * 128; ++nt; }
        }
        *ntile = nt;
    }
}

// ---------------------------------------------------------------------------
// 3) Scatter: pack selected token rows as bf16 into Xg[pos]
// ---------------------------------------------------------------------------
__global__ __launch_bounds__(256) void scatter_kernel(
    const float* __restrict__ x, const int* __restrict__ topi,
    const float* __restrict__ topv, int* __restrict__ cursor,
    float* __restrict__ row_w, int* __restrict__ pos_of,
    unsigned short* __restrict__ Xg)
{
    int p = (blockIdx.x << 2) + (threadIdx.x >> 6);
    int lane = threadIdx.x & 63;
    if (p >= NROWS) return;
    int n = p >> 1;
    int e = topi[p];
    float w = topv[p];
    int pos = 0;
    if (lane == 0) {
        pos = atomicAdd(&cursor[e], 1);
        row_w[pos] = w;
        pos_of[p] = pos;
    }
    pos = __shfl(pos, 0, 64);
    const float* xr = x + (size_t)n * HDIM;
    unsigned short* dst = Xg + (size_t)pos * HDIM;
#pragma unroll
    for (int it = 0; it < HDIM / 256; ++it) {
        int idx = (it * 64 + lane) * 4;
        float4 v = *reinterpret_cast<const float4*>(&xr[idx]);
        ushort4 o;
        o.x = f2bf(v.x); o.y = f2bf(v.y); o.z = f2bf(v.z); o.w = f2bf(v.w);
        *reinterpret_cast<ushort4*>(&dst[idx]) = o;
    }
}

// ---------------------------------------------------------------------------
// 4) Standalone Wd transpose (FALLBACK when ws too small to hold separate
//    Wdt): fp32 [I][H] -> bf16 Wdt [H][I], 128x64 tiles.
// ---------------------------------------------------------------------------
__global__ __launch_bounds__(256) void transpose_d_kernel(
    const float* __restrict__ Wd, unsigned short* __restrict__ Wdt)
{
    __shared__ unsigned short lds[128 * TLDP];
    const int e = blockIdx.y;
    const int tt = blockIdx.x;            // 0..351
    const int tr = tt / 16, tc = tt % 16; // tr over I (22), tc over H (16)
    const int tid = threadIdx.x;

    const float* s0 = Wd + (size_t)e * IDIM * HDIM;
    tp_read_tile64(s0 + (size_t)(tr * 128) * HDIM + tc * 64, HDIM, tid, lds);
    __syncthreads();
    {
        const int g = tid & 15;
        unsigned short* d0 = Wdt + (size_t)e * HDIM * IDIM + tr * 128 + g * 8;
#pragma unroll
        for (int cb = 0; cb < 4; ++cb) {
            int c = cb * 16 + (tid >> 4);     // h within tile, 0..63
            u16x8 o;
#pragma unroll
            for (int jj = 0; jj < 8; ++jj) o[jj] = lds[(g * 8 + jj) * TLDP + c];
            *reinterpret_cast<u16x8*>(d0 + (size_t)(tc * 64 + c) * IDIM) = o;
        }
    }
}

// ---------------------------------------------------------------------------
// 5) Fused gate+up GEMM, optionally MERGED with the Wd transpose:
//    when n_merged==N_MERGED, blocks interleave in 16-block super-groups
//    (8 gateup + 8 t_d) so t_d's BW streaming hides under gateup's MFMA and
//    gateup's logical id g keeps bid&7 == g&7 (XCD supertile preserved).
//    LDS: one 32KB overlay (As+Bs for GEMM; first 16.9KB for transpose).
//    GEMM config r20-proven: 128x128, BK=64, gload16 + XOR swizzle, 0 confl.
// ---------------------------------------------------------------------------
__global__ __launch_bounds__(256, 4) void gateup_td_kernel(
    const unsigned short* __restrict__ Xg,
    const unsigned short* __restrict__ W2,
    const int* __restrict__ offs,
    const int* __restrict__ ntile, const int* __restrict__ te,
    const int* __restrict__ tm0, unsigned short* __restrict__ hbuf,
    const float* __restrict__ Wd, unsigned short* __restrict__ Wdt,
    int n_merged)
{
    __shared__ unsigned short smem[2 * 128 * 64];   // 32 KB overlay
    unsigned short* As = smem;
    unsigned short* Bs = smem + 128 * 64;

    const int tid = threadIdx.x;
    int bid = blockIdx.x;
    int g;
    if (n_merged) {
        if (bid < n_merged) {
            int group = bid >> 4, within = bid & 15;
            if (within >= 8) {
                // ---- t_d tile: Wd [I][H] -> Wdt [H][I]
                int td = group * 8 + (within - 8);      // 0..2815
                int e = td / 352, tt = td % 352;
                int tr = tt / 16, tc = tt % 16;
                const float* s0 = Wd + (size_t)e * IDIM * HDIM;
                tp_read_tile64(s0 + (size_t)(tr * 128) * HDIM + tc * 64, HDIM, tid, smem);
                __syncthreads();
                const int gg = tid & 15;
                unsigned short* d0 = Wdt + (size_t)e * HDIM * IDIM + tr * 128 + gg * 8;
#pragma unroll
                for (int cb = 0; cb < 4; ++cb) {
                    int c = cb * 16 + (tid >> 4);
                    u16x8 o;
#pragma unroll
                    for (int jj = 0; jj < 8; ++jj) o[jj] = smem[(gg * 8 + jj) * TLDP + c];
                    *reinterpret_cast<u16x8*>(d0 + (size_t)(tc * 64 + c) * IDIM) = o;
                }
                return;
            }
            g = group * 8 + within;                     // 0..2815
        } else {
            g = bid - (n_merged >> 1);                  // 2816..3167
        }
    } else {
        g = bid;
    }

    // ---- gateup (logical id g, 0..GU_NWG-1; g&7 == physical bid&7)
    int xcd = g & 7, rest = g >> 3;
    int wg = xcd * (GU_NWG / 8) + rest;
    int tg = wg / (GU_NYT * GU_TG);
    int r2 = wg % (GU_NYT * GU_TG);
    int ny = r2 >> 3, ti = r2 & 7;
    int t = tg * GU_TG + ti;
    if (t >= *ntile) return;

    const int e = te[t];
    const int m0 = tm0[t];
    const int r1 = offs[e + 1];
    const int n0 = ny * 128;                 // i2 base

    const unsigned short* wb = W2 + (size_t)e * 2 * IDIM * HDIM;

    const int lane = tid & 63, wv = tid >> 6;
    const int wr = (wv >> 1) * 64, wc = (wv & 1) * 64;
    const int lr = lane & 15, kq16 = lane >> 4;

    const int a_row8 = tid >> 3;            // 0..31
    const int a_c16 = tid & 7;

    f32x4 acc[4][4];
#pragma unroll
    for (int m = 0; m < 4; ++m)
#pragma unroll
        for (int n = 0; n < 4; ++n) acc[m][n] = {0.f, 0.f, 0.f, 0.f};

    for (int k0 = 0; k0 < HDIM; k0 += 64) {
        __syncthreads();
#pragma unroll
        for (int ch = 0; ch < 4; ++ch) {
            int row = ch * 32 + a_row8;
            int c16s = a_c16 ^ (row & 7);                  // inverse swizzle on source
            gload16(&Xg[(size_t)(m0 + row) * HDIM + k0 + c16s * 8], &As[ch * 2048 + tid * 8]);
            gload16(&wb[(size_t)(n0 + row) * HDIM + k0 + c16s * 8], &Bs[ch * 2048 + tid * 8]);
        }
        __syncthreads();

#pragma unroll
        for (int ks = 0; ks < 2; ++ks) {
            bf16x8 af[4], bf[4];
#pragma unroll
            for (int m = 0; m < 4; ++m) {
                int row = wr + m * 16 + lr;
                int sw = (ks * 4 + kq16) ^ (row & 7);
                af[m] = *reinterpret_cast<const bf16x8*>(&As[row * 64 + sw * 8]);
            }
#pragma unroll
            for (int n = 0; n < 4; ++n) {
                int row = wc + n * 16 + lr;
                int sw = (ks * 4 + kq16) ^ (row & 7);
                bf[n] = *reinterpret_cast<const bf16x8*>(&Bs[row * 64 + sw * 8]);
            }
#pragma unroll
            for (int m = 0; m < 4; ++m)
#pragma unroll
                for (int n = 0; n < 4; ++n)
                    acc[m][n] = __builtin_amdgcn_mfma_f32_16x16x32_bf16(af[m], bf[n], acc[m][n], 0, 0, 0);
        }
    }

    // epilogue: frag parity n even = gate, n odd = up (same lane, same i)
    const int rr = (lane >> 4) * 4;
    const int iloc0 = ((wc >> 5) << 4) + lr;
    const int col0 = ny * 64 + iloc0;
#pragma unroll
    for (int m = 0; m < 4; ++m) {
#pragma unroll
        for (int j = 0; j < 4; ++j) {
            int grow = m0 + wr + m * 16 + rr + j;
            if (grow < r1) {
                unsigned short* hr = &hbuf[(size_t)grow * IDIM + col0];
                float g0 = acc[m][0][j], u0 = acc[m][1][j];
                float g1 = acc[m][2][j], u1 = acc[m][3][j];
                hr[0]  = f2bf(g0 / (1.0f + __expf(-g0)) * u0);
                hr[16] = f2bf(g1 / (1.0f + __expf(-g1)) * u1);
            }
        }
    }
}

// ---------------------------------------------------------------------------
// 6) Down GEMM: gateup's exact 128x128 structure, K=IDIM, no atomics.
//    2-level supertile (r13-proven): xcd=bid&7, rest=bid>>3; tg=rest>>3,
//    ny=rest&7, t=xcd*9+tg.
// ---------------------------------------------------------------------------
__global__ __launch_bounds__(256, 4) void down_kernel(
    const unsigned short* __restrict__ hbuf,
    const unsigned short* __restrict__ Wdt,   // [e][h][i] bf16
    const int* __restrict__ offs,
    const int* __restrict__ ntile, const int* __restrict__ te,
    const int* __restrict__ tm0,
    const float* __restrict__ row_w,
    unsigned short* __restrict__ eobuf)
{
    __shared__ unsigned short As[128 * 64];
    __shared__ unsigned short Bs[128 * 64];

    int bid = blockIdx.x;                          // 576 = 8*72
    int xcd = bid & 7, rest = bid >> 3;            // rest 0..71
    int tg = rest >> 3, ny = rest & 7;
    int t = xcd * 9 + tg;                          // 0..71
    if (t >= *ntile) return;

    const int e = te[t];
    const int m0 = tm0[t];
    const int r1 = offs[e + 1];
    const int n0 = ny * 128;

    const unsigned short* wd = Wdt + (size_t)e * HDIM * IDIM;

    const int tid = threadIdx.x;
    const int lane = tid & 63, wv = tid >> 6;
    const int wr = (wv >> 1) * 64, wc = (wv & 1) * 64;
    const int lr = lane & 15, kq16 = lane >> 4;

    const int a_row8 = tid >> 3;
    const int a_c16 = tid & 7;

    f32x4 acc[4][4];
#pragma unroll
    for (int m = 0; m < 4; ++m)
#pragma unroll
        for (int n = 0; n < 4; ++n) acc[m][n] = {0.f, 0.f, 0.f, 0.f};

    for (int k0 = 0; k0 < IDIM; k0 += 64) {
        __syncthreads();
#pragma unroll
        for (int ch = 0; ch < 4; ++ch) {
            int row = ch * 32 + a_row8;
            int c16s = a_c16 ^ (row & 7);
            gload16(&hbuf[(size_t)(m0 + row) * IDIM + k0 + c16s * 8], &As[ch * 2048 + tid * 8]);
            gload16(&wd[(size_t)(n0 + row) * IDIM + k0 + c16s * 8], &Bs[ch * 2048 + tid * 8]);
        }
        __syncthreads();

#pragma unroll
        for (int ks = 0; ks < 2; ++ks) {
            bf16x8 af[4], bf[4];
#pragma unroll
            for (int m = 0; m < 4; ++m) {
                int row = wr + m * 16 + lr;
                int sw = (ks * 4 + kq16) ^ (row & 7);
                af[m] = *reinterpret_cast<const bf16x8*>(&As[row * 64 + sw * 8]);
            }
#pragma unroll
            for (int n = 0; n < 4; ++n) {
                int row = wc + n * 16 + lr;
                int sw = (ks * 4 + kq16) ^ (row & 7);
                bf[n] = *reinterpret_cast<const bf16x8*>(&Bs[row * 64 + sw * 8]);
            }
#pragma unroll
            for (int m = 0; m < 4; ++m)
#pragma unroll
                for (int n = 0; n < 4; ++n)
                    acc[m][n] = __builtin_amdgcn_mfma_f32_16x16x32_bf16(af[m], bf[n], acc[m][n], 0, 0, 0);
        }
    }

    const int rr = (lane >> 4) * 4;
#pragma unroll
    for (int m = 0; m < 4; ++m) {
#pragma unroll
        for (int j = 0; j < 4; ++j) {
            int grow = m0 + wr + m * 16 + rr + j;
            if (grow < r1) {
                float w = row_w[grow];
                unsigned short* er = &eobuf[(size_t)grow * HDIM + n0 + wc + lr];
#pragma unroll
                for (int n = 0; n < 4; ++n)
                    er[n * 16] = f2bf(acc[m][n][j] * w);
            }
        }
    }
}

// ---------------------------------------------------------------------------
// 7) Combine: out[n] = eobuf[pos0] + eobuf[pos1]
// ---------------------------------------------------------------------------
__global__ __launch_bounds__(256) void combine_kernel(
    const unsigned short* __restrict__ eobuf, const int* __restrict__ pos_of,
    float* __restrict__ out)
{
    int t = blockIdx.x * 256 + threadIdx.x;
    int n = t >> 7;
    int c = (t & 127) << 3;
    int p0 = pos_of[n * 2 + 0];
    int p1 = pos_of[n * 2 + 1];
    uint4 a = *reinterpret_cast<const uint4*>(&eobuf[(size_t)p0 * HDIM + c]);
    uint4 b = *reinterpret_cast<const uint4*>(&eobuf[(size_t)p1 * HDIM + c]);
    float4 o0, o1;
    o0.x = bf2f(a.x & 0xffffu) + bf2f(b.x & 0xffffu);
    o0.y = bf2f(a.x >> 16)     + bf2f(b.x >> 16);
    o0.z = bf2f(a.y & 0xffffu) + bf2f(b.y & 0xffffu);
    o0.w = bf2f(a.y >> 16)     + bf2f(b.y >> 16);
    o1.x = bf2f(a.z & 0xffffu) + bf2f(b.z & 0xffffu);
    o1.y = bf2f(a.z >> 16)     + bf2f(b.z >> 16);
    o1.z = bf2f(a.w & 0xffffu) + bf2f(b.w & 0xffffu);
    o1.w = bf2f(a.w >> 16)     + bf2f(b.w >> 16);
    float* op = out + (size_t)n * HDIM + c;
    *reinterpret_cast<float4*>(op) = o0;
    *reinterpret_cast<float4*>(op + 4) = o1;
}

// ---------------------------------------------------------------------------
// ws layout (bytes):
//   [0,          17,039,360)   Xg bf16 [RPAD][HDIM]   (aliased by eobuf)
//   [17,039,360, 63,897,600)   hbuf bf16 [RPAD][IDIM]
//   [63,897,600, 156,172,288)  W2 bf16 [E][2I][H]
//   big ws: [156,172,288, 202,309,632) Wdt bf16 [E][H][I]; meta at 202,309,632
//           (t_d merged into gateup launch -- no alias, no race)
//   small ws: Wdt aliases W2 (serial t_d after gateup); meta at 156,172,288
// ---------------------------------------------------------------------------
extern "C" void kernel_launch(void* const* d_in, const int* in_sizes, int n_in,
                              void* d_out, int out_size, void* d_ws, size_t ws_size,
                              hipStream_t stream)
{
    const float* x     = (const float*)d_in[0];
    const float* Wgate = (const float*)d_in[1];
    const float* bgate = (const float*)d_in[2];
    const float* Wg    = (const float*)d_in[3];
    const float* Wu    = (const float*)d_in[4];
    const float* Wd    = (const float*)d_in[5];
    float* out = (float*)d_out;
    float* logits = out + (size_t)NTOK * HDIM;

    char* ws = (char*)d_ws;
    unsigned short* Xg   = (unsigned short*)ws;                // also eobuf
    unsigned short* hbuf = (unsigned short*)(ws + 17039360);
    unsigned short* W2   = (unsigned short*)(ws + 63897600);

    const bool big = ws_size >= (size_t)202309632 + 262144;
    unsigned short* Wdt = big ? (unsigned short*)(ws + 156172288) : W2;
    char* meta = ws + (big ? 202309632 : 156172288);

    int*   counts  = (int*)(meta);
    int*   offs    = (int*)(meta + 64);
    int*   cursor  = (int*)(meta + 128);
    int*   ntile   = (int*)(meta + 192);
    int*   te      = (int*)(meta + 256);      // 128 ints
    int*   tm0     = (int*)(meta + 768);      // 128 ints
    int*   topi    = (int*)(meta + 4096);     // NROWS ints
    float* topv    = (float*)(meta + 36864);
    float* row_w   = (float*)(meta + 69632);
    int*   pos_of  = (int*)(meta + 102400);

    hipMemsetAsync(counts, 0, 32, stream);

    // gating blocks first, then Wg/Wu transpose blocks (gating hides in stream)
    prep_kernel<<<N_GATE + N_TGU, 256, 0, stream>>>(
        Wg, Wu, W2, x, Wgate, bgate, logits, counts, topi, topv);

    offsets_kernel<<<1, 64, 0, stream>>>(counts, offs, cursor, ntile, te, tm0);
    scatter_kernel<<<NROWS / 4, 256, 0, stream>>>(x, topi, topv, cursor, row_w, pos_of, Xg);

    if (big) {
        // gateup + Wd-transpose merged (interleaved 8-groups; separate Wdt)
        gateup_td_kernel<<<N_MERGED + (GU_NWG - N_MERGED / 2), 256, 0, stream>>>(
            Xg, W2, offs, ntile, te, tm0, hbuf, Wd, Wdt, N_MERGED);
    } else {
        gateup_td_kernel<<<GU_NWG, 256, 0, stream>>>(
            Xg, W2, offs, ntile, te, tm0, hbuf, Wd, Wdt, 0);
        // fallback: serial Wd transpose aliasing W2 (dead after gateup)
        transpose_d_kernel<<<dim3(352, NEXP), 256, 0, stream>>>(Wd, Wdt);
    }

    // down writes weighted bf16 rows to eobuf (= Xg region, dead after gateup)
    down_kernel<<<DN_NWG, 256, 0, stream>>>(hbuf, Wdt, offs, ntile, te, tm0,
                                            row_w, Xg /*eobuf*/);

    combine_kernel<<<NTOK * HDIM / 8 / 256, 256, 0, stream>>>(Xg, pos_of, out);
}

// Round 22
// 450.161 us; speedup vs baseline: 1.1215x; 1.1215x over previous
//
#include <hip/hip_runtime.h>

// Problem constants
#define HDIM 1024
#define IDIM 2816
#define NEXP 8
#define NTOK 4096      // B*S
#define NROWS 8192     // NTOK * K(=2)
#define RPAD 8320      // Xg/hbuf pad rows
#define MAXT 71        // max total 128-row tiles
#define GU_NYT 44      // 2*IDIM/128
#define GU_TG 8        // gateup supertile: t-group size
#define GU_NTG 9       // ceil(MAXT/GU_TG)
#define GU_NWG (GU_NTG * GU_NYT * GU_TG)   // 3168 = 8*396
#define DN_NWG 576                         // 8 XCD * 9 tg * 8 ny
#define TLDP 66        // transpose LDS pad (shorts), 128x64 tile -> 16.9KB
#define N_TGU 5632     // 2 kinds * 8 experts * 352 tiles (128x64)
#define N_GATE 1024    // NTOK/4  (gating blocks FIRST in the prep grid)

typedef short bf16x8 __attribute__((ext_vector_type(8)));
typedef float f32x4 __attribute__((ext_vector_type(4)));
typedef unsigned short u16x8 __attribute__((ext_vector_type(8)));

static __device__ __forceinline__ float bf2f(unsigned int u) {
    union { unsigned int i; float f; } v; v.i = u << 16; return v.f;
}
static __device__ __forceinline__ unsigned short f2bf(float f) {
    union { float f; unsigned int i; } v; v.f = f;
    return (unsigned short)((v.i + 0x7fffu + ((v.i >> 16) & 1u)) >> 16);  // RNE
}

// async global->LDS, 16B/lane; LDS dest = wave-uniform base + lane*16
static __device__ __forceinline__ void gload16(const void* g, void* l) {
    __builtin_amdgcn_global_load_lds(
        (const __attribute__((address_space(1))) unsigned int*)g,
        (__attribute__((address_space(3))) unsigned int*)l, 16, 0, 0);
}

// ---------------------------------------------------------------------------
// transpose phase-1: coalesced 128x64 fp32 tile read (8192 floats;
// 256 thr x 8 q x 4 floats). Per wave instr: 1 KB over 4 rows (256B/row).
// ---------------------------------------------------------------------------
static __device__ __forceinline__ void tp_read_tile64(
    const float* __restrict__ sp, int C, int tid, unsigned short* lds)
{
#pragma unroll
    for (int q = 0; q < 8; ++q) {
        int idx = q * 1024 + tid * 4;
        int r = idx >> 6, cc = idx & 63;
        float4 v = *reinterpret_cast<const float4*>(sp + (size_t)r * C + cc);
        unsigned w0 = (unsigned)f2bf(v.x) | ((unsigned)f2bf(v.y) << 16);
        unsigned w1 = (unsigned)f2bf(v.z) | ((unsigned)f2bf(v.w) << 16);
        unsigned* lp = reinterpret_cast<unsigned*>(&lds[r * TLDP + cc]);
        lp[0] = w0; lp[1] = w1;
    }
}

// ---------------------------------------------------------------------------
// 1) Prep: gating (blocks [0,N_GATE) -- FIRST, so its latency tail hides
//    under the transpose stream) + Wg/Wu transpose (blocks [N_GATE,+N_TGU)).
//    128x64 tiles (16.9KB LDS -> 8 blocks/CU).
// ---------------------------------------------------------------------------
__global__ __launch_bounds__(256) void prep_kernel(
    const float* __restrict__ Wg, const float* __restrict__ Wu,
    unsigned short* __restrict__ W2,
    const float* __restrict__ x, const float* __restrict__ Wgate,
    const float* __restrict__ bgate, float* __restrict__ logits_out,
    int* __restrict__ counts, int* __restrict__ topi, float* __restrict__ topv)
{
    __shared__ unsigned short lds[128 * TLDP];
    const int b = blockIdx.x;
    const int tid = threadIdx.x;

    if (b >= N_GATE) {
        // ---- Wg/Wu -> interleaved bf16 W2[e][2I][H]; tile = 128 h x 64 i
        const int tno = b - N_GATE;
        const int kind = tno / (NEXP * 352);
        const int rem = tno % (NEXP * 352);
        const int e = rem / 352;
        const int tt = rem % 352;
        const int tr = tt / 44, tc = tt % 44;   // tr over H(8), tc over I(44)

        const float* s0 = (kind ? Wu : Wg) + (size_t)e * HDIM * IDIM;
        tp_read_tile64(s0 + (size_t)(tr * 128) * IDIM + tc * 64, IDIM, tid, lds);
        __syncthreads();
        const int g = tid & 15;
        unsigned short* d0 = W2 + (size_t)e * 2 * IDIM * HDIM + tr * 128 + g * 8;
#pragma unroll
        for (int cb = 0; cb < 4; ++cb) {
            int c = cb * 16 + (tid >> 4);       // i within tile, 0..63
            u16x8 o;
#pragma unroll
            for (int jj = 0; jj < 8; ++jj) o[jj] = lds[(g * 8 + jj) * TLDP + c];
            int i = tc * 64 + c;
            int r2 = ((i >> 4) << 5) + (kind << 4) + (i & 15);
            *reinterpret_cast<u16x8*>(d0 + (size_t)r2 * HDIM) = o;
        }
        return;
    }

    // ---- gating: 4 tokens per block, fp64 accumulate for stable top-2
    int wave = (b << 2) + (tid >> 6);
    int lane = tid & 63;
    if (wave >= NTOK) return;
    const float* xr = x + (size_t)wave * HDIM;

    double acc[NEXP];
#pragma unroll
    for (int e = 0; e < NEXP; ++e) acc[e] = 0.0;
    for (int it = 0; it < HDIM / 64; ++it) {
        int h = lane + (it << 6);
        float xv = xr[h];
        const float* wr = Wgate + (size_t)h * NEXP;
#pragma unroll
        for (int e = 0; e < NEXP; ++e) acc[e] += (double)xv * (double)wr[e];
    }
#pragma unroll
    for (int e = 0; e < NEXP; ++e) {
        double v = acc[e];
        for (int off = 32; off; off >>= 1) v += __shfl_xor(v, off, 64);
        acc[e] = v + (double)bgate[e];
    }
    float lf[NEXP];
#pragma unroll
    for (int e = 0; e < NEXP; ++e) lf[e] = (float)acc[e];

    if (lane < NEXP) logits_out[(size_t)wave * NEXP + lane] = lf[lane];

    if (lane == 0) {
        int i1 = 0; float v1 = lf[0];
#pragma unroll
        for (int e = 1; e < NEXP; ++e) if (lf[e] > v1) { v1 = lf[e]; i1 = e; }
        int i2 = -1; float v2 = -3.0e38f;
#pragma unroll
        for (int e = 0; e < NEXP; ++e) {
            if (e == i1) continue;
            if (lf[e] > v2) { v2 = lf[e]; i2 = e; }
        }
        topi[wave * 2 + 0] = i1; topv[wave * 2 + 0] = v1;
        topi[wave * 2 + 1] = i2; topv[wave * 2 + 1] = v2;
        atomicAdd(&counts[i1], 1);
        atomicAdd(&counts[i2], 1);
    }
}

// ---------------------------------------------------------------------------
// 2) Offsets + device-built tile table (e, m0) per 128-row tile
// ---------------------------------------------------------------------------
__global__ void offsets_kernel(const int* __restrict__ counts,
                               int* __restrict__ offs, int* __restrict__ cursor,
                               int* __restrict__ ntile, int* __restrict__ te,
                               int* __restrict__ tm0)
{
    if (threadIdx.x == 0 && blockIdx.x == 0) {
        int s = 0;
        for (int e = 0; e < NEXP; ++e) { offs[e] = s; cursor[e] = s; s += counts[e]; }
        offs[NEXP] = s;
        int nt = 0;
        for (int e = 0; e < NEXP; ++e) {
            int c = counts[e], base = offs[e];
            for (int mt = 0; mt * 128 < c; ++mt) { te[nt] = e; tm0[nt] = base + mt * 128; ++nt; }
        }
        *ntile = nt;
    }
}

// ---------------------------------------------------------------------------
// 3) Scatter: pack selected token rows as bf16 into Xg[pos]
// ---------------------------------------------------------------------------
__global__ __launch_bounds__(256) void scatter_kernel(
    const float* __restrict__ x, const int* __restrict__ topi,
    const float* __restrict__ topv, int* __restrict__ cursor,
    float* __restrict__ row_w, int* __restrict__ pos_of,
    unsigned short* __restrict__ Xg)
{
    int p = (blockIdx.x << 2) + (threadIdx.x >> 6);
    int lane = threadIdx.x & 63;
    if (p >= NROWS) return;
    int n = p >> 1;
    int e = topi[p];
    float w = topv[p];
    int pos = 0;
    if (lane == 0) {
        pos = atomicAdd(&cursor[e], 1);
        row_w[pos] = w;
        pos_of[p] = pos;
    }
    pos = __shfl(pos, 0, 64);
    const float* xr = x + (size_t)n * HDIM;
    unsigned short* dst = Xg + (size_t)pos * HDIM;
#pragma unroll
    for (int it = 0; it < HDIM / 256; ++it) {
        int idx = (it * 64 + lane) * 4;
        float4 v = *reinterpret_cast<const float4*>(&xr[idx]);
        ushort4 o;
        o.x = f2bf(v.x); o.y = f2bf(v.y); o.z = f2bf(v.z); o.w = f2bf(v.w);
        *reinterpret_cast<ushort4*>(&dst[idx]) = o;
    }
}

// ---------------------------------------------------------------------------
// 4) Wd transpose, 128x64 tiles: fp32 [I][H] -> bf16 Wdt [H][I]
// ---------------------------------------------------------------------------
__global__ __launch_bounds__(256) void transpose_d_kernel(
    const float* __restrict__ Wd, unsigned short* __restrict__ Wdt)
{
    __shared__ unsigned short lds[128 * TLDP];
    const int e = blockIdx.y;
    const int tt = blockIdx.x;            // 0..351
    const int tr = tt / 16, tc = tt % 16; // tr over I (22), tc over H (16)
    const int tid = threadIdx.x;

    const float* s0 = Wd + (size_t)e * IDIM * HDIM;
    tp_read_tile64(s0 + (size_t)(tr * 128) * HDIM + tc * 64, HDIM, tid, lds);
    __syncthreads();
    {
        const int g = tid & 15;
        unsigned short* d0 = Wdt + (size_t)e * HDIM * IDIM + tr * 128 + g * 8;
#pragma unroll
        for (int cb = 0; cb < 4; ++cb) {
            int c = cb * 16 + (tid >> 4);     // h within tile, 0..63
            u16x8 o;
#pragma unroll
            for (int jj = 0; jj < 8; ++jj) o[jj] = lds[(g * 8 + jj) * TLDP + c];
            *reinterpret_cast<u16x8*>(d0 + (size_t)(tc * 64 + c) * IDIM) = o;
        }
    }
}

// ---------------------------------------------------------------------------
// 5) Fused gate+up GEMM over bf16 W2 (interleaved 16g/16u columns):
//    128x128 tile, BK=64, 4 waves, all-gload16 staging with XOR-pre-swizzled
//    SOURCE (both sides, rule #21) + swizzled ds_read_b128 frag reads.
//    L2 supertile: tg of 8 tiles, ny outer / ti inner; bijective XCD chunk.
//    (Proven config: ~118 us, MfmaUtil 37%, conflicts 0, FETCH 116 MB.)
// ---------------------------------------------------------------------------
__global__ __launch_bounds__(256, 4) void gateup_kernel(
    const unsigned short* __restrict__ Xg,
    const unsigned short* __restrict__ W2,
    const int* __restrict__ offs,
    const int* __restrict__ ntile, const int* __restrict__ te,
    const int* __restrict__ tm0, unsigned short* __restrict__ hbuf)
{
    __shared__ unsigned short As[128 * 64];
    __shared__ unsigned short Bs[128 * 64];

    int bid = blockIdx.x;
    int xcd = bid & 7, rest = bid >> 3;
    int wg = xcd * (GU_NWG / 8) + rest;
    int tg = wg / (GU_NYT * GU_TG);
    int r2 = wg % (GU_NYT * GU_TG);
    int ny = r2 >> 3, ti = r2 & 7;
    int t = tg * GU_TG + ti;
    if (t >= *ntile) return;

    const int e = te[t];
    const int m0 = tm0[t];
    const int r1 = offs[e + 1];
    const int n0 = ny * 128;                 // i2 base

    const unsigned short* wb = W2 + (size_t)e * 2 * IDIM * HDIM;

    const int tid = threadIdx.x;
    const int lane = tid & 63, wv = tid >> 6;
    const int wr = (wv >> 1) * 64, wc = (wv & 1) * 64;
    const int lr = lane & 15, kq16 = lane >> 4;

    const int a_row8 = tid >> 3;            // 0..31
    const int a_c16 = tid & 7;

    f32x4 acc[4][4];
#pragma unroll
    for (int m = 0; m < 4; ++m)
#pragma unroll
        for (int n = 0; n < 4; ++n) acc[m][n] = {0.f, 0.f, 0.f, 0.f};

    for (int k0 = 0; k0 < HDIM; k0 += 64) {
        __syncthreads();
#pragma unroll
        for (int ch = 0; ch < 4; ++ch) {
            int row = ch * 32 + a_row8;
            int c16s = a_c16 ^ (row & 7);                  // inverse swizzle on source
            gload16(&Xg[(size_t)(m0 + row) * HDIM + k0 + c16s * 8], &As[ch * 2048 + tid * 8]);
            gload16(&wb[(size_t)(n0 + row) * HDIM + k0 + c16s * 8], &Bs[ch * 2048 + tid * 8]);
        }
        __syncthreads();

#pragma unroll
        for (int ks = 0; ks < 2; ++ks) {
            bf16x8 af[4], bf[4];
#pragma unroll
            for (int m = 0; m < 4; ++m) {
                int row = wr + m * 16 + lr;
                int sw = (ks * 4 + kq16) ^ (row & 7);
                af[m] = *reinterpret_cast<const bf16x8*>(&As[row * 64 + sw * 8]);
            }
#pragma unroll
            for (int n = 0; n < 4; ++n) {
                int row = wc + n * 16 + lr;
                int sw = (ks * 4 + kq16) ^ (row & 7);
                bf[n] = *reinterpret_cast<const bf16x8*>(&Bs[row * 64 + sw * 8]);
            }
#pragma unroll
            for (int m = 0; m < 4; ++m)
#pragma unroll
                for (int n = 0; n < 4; ++n)
                    acc[m][n] = __builtin_amdgcn_mfma_f32_16x16x32_bf16(af[m], bf[n], acc[m][n], 0, 0, 0);
        }
    }

    // epilogue: frag parity n even = gate, n odd = up (same lane, same i)
    const int rr = (lane >> 4) * 4;
    const int iloc0 = ((wc >> 5) << 4) + lr;
    const int col0 = ny * 64 + iloc0;
#pragma unroll
    for (int m = 0; m < 4; ++m) {
#pragma unroll
        for (int j = 0; j < 4; ++j) {
            int grow = m0 + wr + m * 16 + rr + j;
            if (grow < r1) {
                unsigned short* hr = &hbuf[(size_t)grow * IDIM + col0];
                float g0 = acc[m][0][j], u0 = acc[m][1][j];
                float g1 = acc[m][2][j], u1 = acc[m][3][j];
                hr[0]  = f2bf(g0 / (1.0f + __expf(-g0)) * u0);
                hr[16] = f2bf(g1 / (1.0f + __expf(-g1)) * u1);
            }
        }
    }
}

// ---------------------------------------------------------------------------
// 6) Down GEMM: gateup's exact 128x128 structure, K=IDIM, no atomics.
//    2-level supertile (r13-proven): xcd=bid&7, rest=bid>>3; tg=rest>>3,
//    ny=rest&7, t=xcd*9+tg. The 8 blocks sharing A-tile t are consecutive on
//    the SAME XCD (tile read once into L2, 8x reuse).
// ---------------------------------------------------------------------------
__global__ __launch_bounds__(256, 4) void down_kernel(
    const unsigned short* __restrict__ hbuf,
    const unsigned short* __restrict__ Wdt,   // [e][h][i] bf16
    const int* __restrict__ offs,
    const int* __restrict__ ntile, const int* __restrict__ te,
    const int* __restrict__ tm0,
    const float* __restrict__ row_w,
    unsigned short* __restrict__ eobuf)
{
    __shared__ unsigned short As[128 * 64];
    __shared__ unsigned short Bs[128 * 64];

    int bid = blockIdx.x;                          // 576 = 8*72
    int xcd = bid & 7, rest = bid >> 3;            // rest 0..71
    int tg = rest >> 3, ny = rest & 7;
    int t = xcd * 9 + tg;                          // 0..71
    if (t >= *ntile) return;

    const int e = te[t];
    const int m0 = tm0[t];
    const int r1 = offs[e + 1];
    const int n0 = ny * 128;

    const unsigned short* wd = Wdt + (size_t)e * HDIM * IDIM;

    const int tid = threadIdx.x;
    const int lane = tid & 63, wv = tid >> 6;
    const int wr = (wv >> 1) * 64, wc = (wv & 1) * 64;
    const int lr = lane & 15, kq16 = lane >> 4;

    const int a_row8 = tid >> 3;
    const int a_c16 = tid & 7;

    f32x4 acc[4][4];
#pragma unroll
    for (int m = 0; m < 4; ++m)
#pragma unroll
        for (int n = 0; n < 4; ++n) acc[m][n] = {0.f, 0.f, 0.f, 0.f};

    for (int k0 = 0; k0 < IDIM; k0 += 64) {
        __syncthreads();
#pragma unroll
        for (int ch = 0; ch < 4; ++ch) {
            int row = ch * 32 + a_row8;
            int c16s = a_c16 ^ (row & 7);
            gload16(&hbuf[(size_t)(m0 + row) * IDIM + k0 + c16s * 8], &As[ch * 2048 + tid * 8]);
            gload16(&wd[(size_t)(n0 + row) * IDIM + k0 + c16s * 8], &Bs[ch * 2048 + tid * 8]);
        }
        __syncthreads();

#pragma unroll
        for (int ks = 0; ks < 2; ++ks) {
            bf16x8 af[4], bf[4];
#pragma unroll
            for (int m = 0; m < 4; ++m) {
                int row = wr + m * 16 + lr;
                int sw = (ks * 4 + kq16) ^ (row & 7);
                af[m] = *reinterpret_cast<const bf16x8*>(&As[row * 64 + sw * 8]);
            }
#pragma unroll
            for (int n = 0; n < 4; ++n) {
                int row = wc + n * 16 + lr;
                int sw = (ks * 4 + kq16) ^ (row & 7);
                bf[n] = *reinterpret_cast<const bf16x8*>(&Bs[row * 64 + sw * 8]);
            }
#pragma unroll
            for (int m = 0; m < 4; ++m)
#pragma unroll
                for (int n = 0; n < 4; ++n)
                    acc[m][n] = __builtin_amdgcn_mfma_f32_16x16x32_bf16(af[m], bf[n], acc[m][n], 0, 0, 0);
        }
    }

    const int rr = (lane >> 4) * 4;
#pragma unroll
    for (int m = 0; m < 4; ++m) {
#pragma unroll
        for (int j = 0; j < 4; ++j) {
            int grow = m0 + wr + m * 16 + rr + j;
            if (grow < r1) {
                float w = row_w[grow];
                unsigned short* er = &eobuf[(size_t)grow * HDIM + n0 + wc + lr];
#pragma unroll
                for (int n = 0; n < 4; ++n)
                    er[n * 16] = f2bf(acc[m][n][j] * w);
            }
        }
    }
}

// ---------------------------------------------------------------------------
// 7) Combine: out[n] = eobuf[pos0] + eobuf[pos1]
// ---------------------------------------------------------------------------
__global__ __launch_bounds__(256) void combine_kernel(
    const unsigned short* __restrict__ eobuf, const int* __restrict__ pos_of,
    float* __restrict__ out)
{
    int t = blockIdx.x * 256 + threadIdx.x;
    int n = t >> 7;
    int c = (t & 127) << 3;
    int p0 = pos_of[n * 2 + 0];
    int p1 = pos_of[n * 2 + 1];
    uint4 a = *reinterpret_cast<const uint4*>(&eobuf[(size_t)p0 * HDIM + c]);
    uint4 b = *reinterpret_cast<const uint4*>(&eobuf[(size_t)p1 * HDIM + c]);
    float4 o0, o1;
    o0.x = bf2f(a.x & 0xffffu) + bf2f(b.x & 0xffffu);
    o0.y = bf2f(a.x >> 16)     + bf2f(b.x >> 16);
    o0.z = bf2f(a.y & 0xffffu) + bf2f(b.y & 0xffffu);
    o0.w = bf2f(a.y >> 16)     + bf2f(b.y >> 16);
    o1.x = bf2f(a.z & 0xffffu) + bf2f(b.z & 0xffffu);
    o1.y = bf2f(a.z >> 16)     + bf2f(b.z >> 16);
    o1.z = bf2f(a.w & 0xffffu) + bf2f(b.w & 0xffffu);
    o1.w = bf2f(a.w >> 16)     + bf2f(b.w >> 16);
    float* op = out + (size_t)n * HDIM + c;
    *reinterpret_cast<float4*>(op) = o0;
    *reinterpret_cast<float4*>(op + 4) = o1;
}

// ---------------------------------------------------------------------------
// ws layout (bytes):
//   [0,          17,039,360)   Xg bf16 [RPAD][HDIM]   (aliased by eobuf)
//   [17,039,360, 63,897,600)   hbuf bf16 [RPAD][IDIM]
//   [63,897,600, 156,172,288)  W2 bf16 [E][2I][H]  (aliased by Wdt after gateup)
//   [156,172,288, ...)         meta
// ---------------------------------------------------------------------------
extern "C" void kernel_launch(void* const* d_in, const int* in_sizes, int n_in,
                              void* d_out, int out_size, void* d_ws, size_t ws_size,
                              hipStream_t stream)
{
    const float* x     = (const float*)d_in[0];
    const float* Wgate = (const float*)d_in[1];
    const float* bgate = (const float*)d_in[2];
    const float* Wg    = (const float*)d_in[3];
    const float* Wu    = (const float*)d_in[4];
    const float* Wd    = (const float*)d_in[5];
    float* out = (float*)d_out;
    float* logits = out + (size_t)NTOK * HDIM;

    char* ws = (char*)d_ws;
    unsigned short* Xg   = (unsigned short*)ws;                // also eobuf
    unsigned short* hbuf = (unsigned short*)(ws + 17039360);
    unsigned short* W2   = (unsigned short*)(ws + 63897600);   // also Wdt
    char* meta = ws + 156172288;
    int*   counts  = (int*)(meta);
    int*   offs    = (int*)(meta + 64);
    int*   cursor  = (int*)(meta + 128);
    int*   ntile   = (int*)(meta + 192);
    int*   te      = (int*)(meta + 256);      // 128 ints
    int*   tm0     = (int*)(meta + 768);      // 128 ints
    int*   topi    = (int*)(meta + 4096);     // NROWS ints
    float* topv    = (float*)(meta + 36864);
    float* row_w   = (float*)(meta + 69632);
    int*   pos_of  = (int*)(meta + 102400);

    hipMemsetAsync(counts, 0, 32, stream);

    // gating blocks first, then Wg/Wu transpose blocks (gating hides in stream)
    prep_kernel<<<N_GATE + N_TGU, 256, 0, stream>>>(
        Wg, Wu, W2, x, Wgate, bgate, logits, counts, topi, topv);

    offsets_kernel<<<1, 64, 0, stream>>>(counts, offs, cursor, ntile, te, tm0);
    scatter_kernel<<<NROWS / 4, 256, 0, stream>>>(x, topi, topv, cursor, row_w, pos_of, Xg);

    gateup_kernel<<<GU_NWG, 256, 0, stream>>>(Xg, W2, offs, ntile, te, tm0, hbuf);

    // Wd fp32 [I][H] -> bf16 [H][I], aliased over W2 (dead after gateup)
    transpose_d_kernel<<<dim3(352, NEXP), 256, 0, stream>>>(Wd, W2);

    // down writes weighted bf16 rows to eobuf (= Xg region, dead after gateup)
    down_kernel<<<DN_NWG, 256, 0, stream>>>(hbuf, W2, offs, ntile, te, tm0,
                                            row_w, Xg /*eobuf*/);

    combine_kernel<<<NTOK * HDIM / 8 / 256, 256, 0, stream>>>(Xg, pos_of, out);
}